// Round 1
// baseline (429.190 us; speedup 1.0000x reference)
//
#include <hip/hip_runtime.h>
#include <hip/hip_bf16.h>

typedef __bf16 bf16x8 __attribute__((ext_vector_type(8)));
typedef float floatx4 __attribute__((ext_vector_type(4)));
typedef unsigned short ushort_t;

// ---- 8-element loads, converting to bf16x8 ----
__device__ __forceinline__ bf16x8 load8(const float* p) {
  const float4* q = reinterpret_cast<const float4*>(p);
  float4 x = q[0], y = q[1];
  bf16x8 r;
  r[0] = (__bf16)x.x; r[1] = (__bf16)x.y; r[2] = (__bf16)x.z; r[3] = (__bf16)x.w;
  r[4] = (__bf16)y.x; r[5] = (__bf16)y.y; r[6] = (__bf16)y.z; r[7] = (__bf16)y.w;
  return r;
}
__device__ __forceinline__ bf16x8 load8(const ushort_t* p) {
  return *reinterpret_cast<const bf16x8*>(p);
}

// ---- epilogue stores ----
__device__ __forceinline__ void storeC(float* C, long idx, float v) { C[idx] = v; }
__device__ __forceinline__ void storeC(ushort_t* C, long idx, float v) {
  __bf16 b = (__bf16)v;
  C[idx] = __builtin_bit_cast(ushort_t, b);
}

// =====================================================================
// NT GEMM: C[m,n] = alpha * sum_k A[m,k]*B[n,k]  (+ bias)
// BIAS_MODE: 0 = none, 1 = bias[n], 2 = bias[m]
// 128x128 tile, BK=32, 256 threads (4 waves), mfma_f32_16x16x32_bf16.
// All M,N,K must be multiples of 128/128/32 (true for every call here).
// =====================================================================
template<typename TA, typename TB, typename TC, int BIAS_MODE>
__global__ __launch_bounds__(256) void gemm_nt(
    const TA* __restrict__ A, const TB* __restrict__ B,
    const float* __restrict__ bias, TC* __restrict__ C,
    int M, int N, int K, float alpha,
    long sAb, long sBb, long sCb)
{
  // rows padded 32 -> 40 bf16 (80 B): keeps ds_read_b128 16B-aligned,
  // 2-way bank aliasing only (free on gfx950).
  __shared__ ushort_t As[128 * 40];
  __shared__ ushort_t Bs[128 * 40];

  const int bz = blockIdx.z;
  A += (long)bz * sAb;
  B += (long)bz * sBb;
  C += (long)bz * sCb;

  const int bm = blockIdx.x, bn = blockIdx.y;
  const int tid = threadIdx.x;
  const int wave = tid >> 6, lane = tid & 63;
  const int wm = (wave & 1) * 64, wn = (wave >> 1) * 64;
  const int lr = lane & 15, lq = lane >> 4;

  const TA* Ab = A + (long)(bm * 128) * K;
  const TB* Bb = B + (long)(bn * 128) * K;

  // staging: 512 8-elt segments per tile per matrix; 2 each per thread
  const int r0 = tid >> 2;             // rows 0..63
  const int k0 = (tid & 3) << 3;       // 0,8,16,24
  const int r1 = r0 + 64;              // rows 64..127

  floatx4 acc[4][4];
  #pragma unroll
  for (int i = 0; i < 4; ++i)
    #pragma unroll
    for (int j = 0; j < 4; ++j)
      acc[i][j] = (floatx4){0.f, 0.f, 0.f, 0.f};

  int aoff[4], boff[4];
  #pragma unroll
  for (int i = 0; i < 4; ++i) {
    aoff[i] = (wm + i * 16 + lr) * 40 + lq * 8;
    boff[i] = (wn + i * 16 + lr) * 40 + lq * 8;
  }

  const int ktiles = K >> 5;
  for (int kt = 0; kt < ktiles; ++kt) {
    const long kb = (long)kt * 32 + k0;
    bf16x8 av0 = load8(Ab + (long)r0 * K + kb);
    bf16x8 av1 = load8(Ab + (long)r1 * K + kb);
    bf16x8 bv0 = load8(Bb + (long)r0 * K + kb);
    bf16x8 bv1 = load8(Bb + (long)r1 * K + kb);
    *reinterpret_cast<bf16x8*>(&As[r0 * 40 + k0]) = av0;
    *reinterpret_cast<bf16x8*>(&As[r1 * 40 + k0]) = av1;
    *reinterpret_cast<bf16x8*>(&Bs[r0 * 40 + k0]) = bv0;
    *reinterpret_cast<bf16x8*>(&Bs[r1 * 40 + k0]) = bv1;
    __syncthreads();

    bf16x8 af[4], bfr[4];
    #pragma unroll
    for (int i = 0; i < 4; ++i)
      af[i] = *reinterpret_cast<const bf16x8*>(&As[aoff[i]]);
    #pragma unroll
    for (int j = 0; j < 4; ++j)
      bfr[j] = *reinterpret_cast<const bf16x8*>(&Bs[boff[j]]);
    #pragma unroll
    for (int i = 0; i < 4; ++i)
      #pragma unroll
      for (int j = 0; j < 4; ++j)
        acc[i][j] = __builtin_amdgcn_mfma_f32_16x16x32_bf16(af[i], bfr[j], acc[i][j], 0, 0, 0);
    __syncthreads();
  }

  // epilogue: C/D layout col=lane&15, row=quad*4+reg (m89-verified)
  #pragma unroll
  for (int i = 0; i < 4; ++i) {
    #pragma unroll
    for (int j = 0; j < 4; ++j) {
      const int row0 = bm * 128 + wm + i * 16 + lq * 4;
      const int col  = bn * 128 + wn + j * 16 + lr;
      #pragma unroll
      for (int r = 0; r < 4; ++r) {
        float v = acc[i][j][r] * alpha;
        if (BIAS_MODE == 1) v += bias[col];
        if (BIAS_MODE == 2) v += bias[row0 + r];
        storeC(C, (long)(row0 + r) * N + col, v);
      }
    }
  }
}

// =====================================================================
// Row softmax with exact reference mask semantics:
//   v = s[j]; if (mask[b,j]==0) v = -1e10; if (j>i) v += -1e10; softmax.
// One 256-thread block per row, S=2048 -> 8 elements/thread.
// =====================================================================
__global__ __launch_bounds__(256) void softmax_causal(
    float* __restrict__ Sc, const int* __restrict__ mask, int S)
{
  const int i = blockIdx.x, b = blockIdx.y;
  float* row = Sc + ((long)b * S + i) * S;
  const int* mrow = mask + (long)b * S;
  const int tid = threadIdx.x;
  const int lane = tid & 63, wave = tid >> 6;
  __shared__ float red[4];

  float vals[8];
  float mymax = -3.4e38f;
  #pragma unroll
  for (int u = 0; u < 8; ++u) {
    const int j = tid + (u << 8);
    float v = row[j];
    if (mrow[j] == 0) v = -1e10f;
    if (j > i) v += -1e10f;
    vals[u] = v;
    mymax = fmaxf(mymax, v);
  }
  #pragma unroll
  for (int off = 32; off; off >>= 1)
    mymax = fmaxf(mymax, __shfl_xor(mymax, off));
  if (lane == 0) red[wave] = mymax;
  __syncthreads();
  const float m = fmaxf(fmaxf(red[0], red[1]), fmaxf(red[2], red[3]));
  __syncthreads();

  float sum = 0.f;
  #pragma unroll
  for (int u = 0; u < 8; ++u) {
    const float e = __expf(vals[u] - m);
    vals[u] = e;
    sum += e;
  }
  #pragma unroll
  for (int off = 32; off; off >>= 1)
    sum += __shfl_xor(sum, off);
  if (lane == 0) red[wave] = sum;
  __syncthreads();
  const float tot = red[0] + red[1] + red[2] + red[3];
  const float inv = 1.0f / tot;
  #pragma unroll
  for (int u = 0; u < 8; ++u) {
    const int j = tid + (u << 8);
    row[j] = vals[u] * inv;
  }
}

extern "C" void kernel_launch(void* const* d_in, const int* in_sizes, int n_in,
                              void* d_out, int out_size, void* d_ws, size_t ws_size,
                              hipStream_t stream)
{
  const int B = 4, S = 2048, D = 1024;
  const float* Q  = (const float*)d_in[0];
  const float* K  = (const float*)d_in[1];
  const float* V  = (const float*)d_in[2];
  const int*   am = (const int*)d_in[3];
  const float* Wq = (const float*)d_in[4];
  const float* bq = (const float*)d_in[5];
  const float* Wk = (const float*)d_in[6];
  const float* bk = (const float*)d_in[7];
  const float* Wv = (const float*)d_in[8];
  const float* bv = (const float*)d_in[9];
  float* out = (float*)d_out;

  const long MS = (long)B * S;                 // 8192 rows
  // workspace: q(16MB) k(16MB) vT(16MB) bf16 + scores 64MB fp32 = 112 MB
  ushort_t* qb = (ushort_t*)d_ws;
  ushort_t* kb = qb + MS * D;
  ushort_t* vT = kb + MS * D;                  // [B][D][S]
  float*    Sc = (float*)(vT + MS * D);        // [B][S][S]

  dim3 blk(256);

  // q = Q·Wq^T + bq  (bias over n)
  gemm_nt<float, float, ushort_t, 1><<<dim3(64, 8, 1), blk, 0, stream>>>(
      Q, Wq, bq, qb, (int)MS, D, D, 1.0f, 0L, 0L, 0L);
  // k = K·Wk^T + bk
  gemm_nt<float, float, ushort_t, 1><<<dim3(64, 8, 1), blk, 0, stream>>>(
      K, Wk, bk, kb, (int)MS, D, D, 1.0f, 0L, 0L, 0L);
  // vT[b,e,s] = sum_d Wv[e,d]*V[b,s,d] + bv[e]  (bias over m), per batch
  gemm_nt<float, float, ushort_t, 2><<<dim3(8, 16, 4), blk, 0, stream>>>(
      Wv, V, bv, vT, D, S, D, 1.0f, 0L, (long)S * D, (long)D * S);
  // Sc_b = q_b · k_b^T / sqrt(D), per batch (full matrix — see mask edge case)
  gemm_nt<ushort_t, ushort_t, float, 0><<<dim3(16, 16, 4), blk, 0, stream>>>(
      qb, kb, nullptr, Sc, S, S, D, 0.03125f,
      (long)S * D, (long)S * D, (long)S * S);
  // softmax with mask + causal (exact reference ordering)
  softmax_causal<<<dim3(S, B), blk, 0, stream>>>(Sc, am, S);
  // O_b = P_b · vT_b^T, per batch
  gemm_nt<float, ushort_t, float, 0><<<dim3(16, 8, 4), blk, 0, stream>>>(
      Sc, vT, nullptr, out, S, D, S, 1.0f,
      (long)S * S, (long)D * S, (long)S * D);
}

// Round 2
// 405.138 us; speedup vs baseline: 1.0594x; 1.0594x over previous
//
#include <hip/hip_runtime.h>
#include <hip/hip_bf16.h>

typedef __bf16 bf16x8 __attribute__((ext_vector_type(8)));
typedef float floatx4 __attribute__((ext_vector_type(4)));
typedef unsigned short ushort_t;

// ---- 8-element loads, converting to bf16x8 ----
__device__ __forceinline__ bf16x8 load8(const float* p) {
  const float4* q = reinterpret_cast<const float4*>(p);
  float4 x = q[0], y = q[1];
  bf16x8 r;
  r[0] = (__bf16)x.x; r[1] = (__bf16)x.y; r[2] = (__bf16)x.z; r[3] = (__bf16)x.w;
  r[4] = (__bf16)y.x; r[5] = (__bf16)y.y; r[6] = (__bf16)y.z; r[7] = (__bf16)y.w;
  return r;
}

// ---- epilogue stores ----
__device__ __forceinline__ void storeC(float* C, long idx, float v) { C[idx] = v; }
__device__ __forceinline__ void storeC(ushort_t* C, long idx, float v) {
  __bf16 b = (__bf16)v;
  C[idx] = __builtin_bit_cast(ushort_t, b);
}

// async global->LDS, 16B per lane (m97 path)
__device__ __forceinline__ void glds16(const ushort_t* g, ushort_t* l) {
  __builtin_amdgcn_global_load_lds(
      (const __attribute__((address_space(1))) void*)g,
      (__attribute__((address_space(3))) void*)l, 16, 0, 0);
}

// =====================================================================
// Register-staged NT GEMM for fp32 inputs (needs convert during staging).
// C[m,n] = alpha * sum_k A[m,k]*B[n,k] (+ bias). BIAS_MODE: 1=bias[n], 2=bias[m]
// =====================================================================
template<int BIAS_MODE>
__global__ __launch_bounds__(256) void gemm_nt_f32in(
    const float* __restrict__ A, const float* __restrict__ B,
    const float* __restrict__ bias, ushort_t* __restrict__ C,
    int M, int N, int K, float alpha,
    long sAb, long sBb, long sCb)
{
  __shared__ ushort_t As[128 * 40];   // padded to 40: 16B-aligned b128, 2-way alias free
  __shared__ ushort_t Bs[128 * 40];

  const int bz = blockIdx.z;
  A += (long)bz * sAb;
  B += (long)bz * sBb;
  C += (long)bz * sCb;

  const int bm = blockIdx.x, bn = blockIdx.y;
  const int tid = threadIdx.x;
  const int wave = tid >> 6, lane = tid & 63;
  const int wm = (wave & 1) * 64, wn = (wave >> 1) * 64;
  const int lr = lane & 15, lq = lane >> 4;

  const float* Ab = A + (long)(bm * 128) * K;
  const float* Bb = B + (long)(bn * 128) * K;

  const int r0 = tid >> 2;
  const int k0 = (tid & 3) << 3;
  const int r1 = r0 + 64;

  floatx4 acc[4][4];
  #pragma unroll
  for (int i = 0; i < 4; ++i)
    #pragma unroll
    for (int j = 0; j < 4; ++j)
      acc[i][j] = (floatx4){0.f, 0.f, 0.f, 0.f};

  int aoff[4], boff[4];
  #pragma unroll
  for (int i = 0; i < 4; ++i) {
    aoff[i] = (wm + i * 16 + lr) * 40 + lq * 8;
    boff[i] = (wn + i * 16 + lr) * 40 + lq * 8;
  }

  const int ktiles = K >> 5;
  for (int kt = 0; kt < ktiles; ++kt) {
    const long kb = (long)kt * 32 + k0;
    bf16x8 av0 = load8(Ab + (long)r0 * K + kb);
    bf16x8 av1 = load8(Ab + (long)r1 * K + kb);
    bf16x8 bv0 = load8(Bb + (long)r0 * K + kb);
    bf16x8 bv1 = load8(Bb + (long)r1 * K + kb);
    *reinterpret_cast<bf16x8*>(&As[r0 * 40 + k0]) = av0;
    *reinterpret_cast<bf16x8*>(&As[r1 * 40 + k0]) = av1;
    *reinterpret_cast<bf16x8*>(&Bs[r0 * 40 + k0]) = bv0;
    *reinterpret_cast<bf16x8*>(&Bs[r1 * 40 + k0]) = bv1;
    __syncthreads();

    bf16x8 af[4], bfr[4];
    #pragma unroll
    for (int i = 0; i < 4; ++i)
      af[i] = *reinterpret_cast<const bf16x8*>(&As[aoff[i]]);
    #pragma unroll
    for (int j = 0; j < 4; ++j)
      bfr[j] = *reinterpret_cast<const bf16x8*>(&Bs[boff[j]]);
    #pragma unroll
    for (int i = 0; i < 4; ++i)
      #pragma unroll
      for (int j = 0; j < 4; ++j)
        acc[i][j] = __builtin_amdgcn_mfma_f32_16x16x32_bf16(af[i], bfr[j], acc[i][j], 0, 0, 0);
    __syncthreads();
  }

  #pragma unroll
  for (int i = 0; i < 4; ++i) {
    #pragma unroll
    for (int j = 0; j < 4; ++j) {
      const int row0 = bm * 128 + wm + i * 16 + lq * 4;
      const int col  = bn * 128 + wn + j * 16 + lr;
      #pragma unroll
      for (int r = 0; r < 4; ++r) {
        float v = acc[i][j][r] * alpha;
        if (BIAS_MODE == 1) v += bias[col];
        if (BIAS_MODE == 2) v += bias[row0 + r];
        storeC(C, (long)(row0 + r) * N + col, v);
      }
    }
  }
}

// =====================================================================
// All-bf16 NT GEMM with async global_load_lds (width 16) staging — m97
// structure. Unpadded LDS (64 B rows): required by the wave-uniform-base
// + lane*16 LDS addressing of global_load_lds.
// C fp32: C[m,n] = alpha * sum_k A[m,k]*B[n,k]
// =====================================================================
__global__ __launch_bounds__(256) void gemm_nt_bf16(
    const ushort_t* __restrict__ A, const ushort_t* __restrict__ B,
    float* __restrict__ C,
    int M, int N, int K, float alpha,
    long sAb, long sBb, long sCb)
{
  __shared__ ushort_t As[128 * 32];   // 8 KB, unpadded
  __shared__ ushort_t Bs[128 * 32];

  const int bz = blockIdx.z;
  A += (long)bz * sAb;
  B += (long)bz * sBb;
  C += (long)bz * sCb;

  const int bm = blockIdx.x, bn = blockIdx.y;
  const int tid = threadIdx.x;
  const int wave = tid >> 6, lane = tid & 63;
  const int wm = (wave & 1) * 64, wn = (wave >> 1) * 64;
  const int lr = lane & 15, lq = lane >> 4;

  const ushort_t* Ab = A + (long)(bm * 128) * K;
  const ushort_t* Bb = B + (long)(bn * 128) * K;

  // staging segment ids: seg = t*256 + tid; row = seg>>2; elem off = (seg&3)*8
  const int seg0 = tid, seg1 = 256 + tid;
  const int sr0 = seg0 >> 2, sk0 = (seg0 & 3) << 3;
  const int sr1 = seg1 >> 2, sk1 = (seg1 & 3) << 3;

  floatx4 acc[4][4];
  #pragma unroll
  for (int i = 0; i < 4; ++i)
    #pragma unroll
    for (int j = 0; j < 4; ++j)
      acc[i][j] = (floatx4){0.f, 0.f, 0.f, 0.f};

  int aoff[4], boff[4];
  #pragma unroll
  for (int i = 0; i < 4; ++i) {
    aoff[i] = (wm + i * 16 + lr) * 32 + lq * 8;
    boff[i] = (wn + i * 16 + lr) * 32 + lq * 8;
  }

  const int ktiles = K >> 5;
  for (int kt = 0; kt < ktiles; ++kt) {
    const int kc = kt << 5;
    glds16(Ab + (long)sr0 * K + kc + sk0, &As[seg0 * 8]);
    glds16(Ab + (long)sr1 * K + kc + sk1, &As[seg1 * 8]);
    glds16(Bb + (long)sr0 * K + kc + sk0, &Bs[seg0 * 8]);
    glds16(Bb + (long)sr1 * K + kc + sk1, &Bs[seg1 * 8]);
    __syncthreads();   // compiler drains vmcnt(0) here

    bf16x8 af[4], bfr[4];
    #pragma unroll
    for (int i = 0; i < 4; ++i)
      af[i] = *reinterpret_cast<const bf16x8*>(&As[aoff[i]]);
    #pragma unroll
    for (int j = 0; j < 4; ++j)
      bfr[j] = *reinterpret_cast<const bf16x8*>(&Bs[boff[j]]);
    #pragma unroll
    for (int i = 0; i < 4; ++i)
      #pragma unroll
      for (int j = 0; j < 4; ++j)
        acc[i][j] = __builtin_amdgcn_mfma_f32_16x16x32_bf16(af[i], bfr[j], acc[i][j], 0, 0, 0);
    __syncthreads();
  }

  #pragma unroll
  for (int i = 0; i < 4; ++i) {
    #pragma unroll
    for (int j = 0; j < 4; ++j) {
      const int row0 = bm * 128 + wm + i * 16 + lq * 4;
      const int col  = bn * 128 + wn + j * 16 + lr;
      #pragma unroll
      for (int r = 0; r < 4; ++r)
        C[(long)(row0 + r) * N + col] = acc[i][j][r] * alpha;
    }
  }
}

// =====================================================================
// Row softmax, exact reference mask ordering; reads fp32 Sc, writes bf16 P.
// =====================================================================
__global__ __launch_bounds__(256) void softmax_causal(
    const float* __restrict__ Sc, ushort_t* __restrict__ P,
    const int* __restrict__ mask, int S)
{
  const int i = blockIdx.x, b = blockIdx.y;
  const float* row = Sc + ((long)b * S + i) * S;
  ushort_t* prow = P + ((long)b * S + i) * S;
  const int* mrow = mask + (long)b * S;
  const int tid = threadIdx.x;
  const int lane = tid & 63, wave = tid >> 6;
  __shared__ float red[4];

  float vals[8];
  float mymax = -3.4e38f;
  #pragma unroll
  for (int u = 0; u < 8; ++u) {
    const int j = tid + (u << 8);
    float v = row[j];
    if (mrow[j] == 0) v = -1e10f;
    if (j > i) v += -1e10f;
    vals[u] = v;
    mymax = fmaxf(mymax, v);
  }
  #pragma unroll
  for (int off = 32; off; off >>= 1)
    mymax = fmaxf(mymax, __shfl_xor(mymax, off));
  if (lane == 0) red[wave] = mymax;
  __syncthreads();
  const float m = fmaxf(fmaxf(red[0], red[1]), fmaxf(red[2], red[3]));
  __syncthreads();

  float sum = 0.f;
  #pragma unroll
  for (int u = 0; u < 8; ++u) {
    const float e = __expf(vals[u] - m);
    vals[u] = e;
    sum += e;
  }
  #pragma unroll
  for (int off = 32; off; off >>= 1)
    sum += __shfl_xor(sum, off);
  if (lane == 0) red[wave] = sum;
  __syncthreads();
  const float tot = red[0] + red[1] + red[2] + red[3];
  const float inv = 1.0f / tot;
  #pragma unroll
  for (int u = 0; u < 8; ++u) {
    const int j = tid + (u << 8);
    __bf16 bv = (__bf16)(vals[u] * inv);
    prow[j] = __builtin_bit_cast(ushort_t, bv);
  }
}

extern "C" void kernel_launch(void* const* d_in, const int* in_sizes, int n_in,
                              void* d_out, int out_size, void* d_ws, size_t ws_size,
                              hipStream_t stream)
{
  const int B = 4, S = 2048, D = 1024;
  const float* Q  = (const float*)d_in[0];
  const float* K  = (const float*)d_in[1];
  const float* V  = (const float*)d_in[2];
  const int*   am = (const int*)d_in[3];
  const float* Wq = (const float*)d_in[4];
  const float* bq = (const float*)d_in[5];
  const float* Wk = (const float*)d_in[6];
  const float* bk = (const float*)d_in[7];
  const float* Wv = (const float*)d_in[8];
  const float* bv = (const float*)d_in[9];
  float* out = (float*)d_out;

  const long MS = (long)B * S;                 // 8192 rows
  // ws: qb(16MB) kb(16MB) vT(16MB) bf16 + Sc 64MB fp32 = 112 MB.
  // P (32MB bf16) aliases qb+kb, which are dead once the scores GEMM ran.
  ushort_t* qb = (ushort_t*)d_ws;
  ushort_t* kb = qb + MS * D;
  ushort_t* vT = kb + MS * D;                  // [B][D][S]
  float*    Sc = (float*)(vT + MS * D);        // [B][S][S]
  ushort_t* P  = qb;                           // [B][S][S] bf16, aliased

  dim3 blk(256);

  // q = Q·Wq^T + bq
  gemm_nt_f32in<1><<<dim3(64, 8, 1), blk, 0, stream>>>(
      Q, Wq, bq, qb, (int)MS, D, D, 1.0f, 0L, 0L, 0L);
  // k = K·Wk^T + bk
  gemm_nt_f32in<1><<<dim3(64, 8, 1), blk, 0, stream>>>(
      K, Wk, bk, kb, (int)MS, D, D, 1.0f, 0L, 0L, 0L);
  // vT[b,e,s] = sum_d Wv[e,d]*V[b,s,d] + bv[e]
  gemm_nt_f32in<2><<<dim3(8, 16, 4), blk, 0, stream>>>(
      Wv, V, bv, vT, D, S, D, 1.0f, 0L, (long)S * D, (long)D * S);
  // Sc_b = q_b · k_b^T / sqrt(D)  (async-staged bf16 GEMM)
  gemm_nt_bf16<<<dim3(16, 16, 4), blk, 0, stream>>>(
      qb, kb, Sc, S, S, D, 0.03125f,
      (long)S * D, (long)S * D, (long)S * S);
  // softmax (mask + causal, reference ordering), P in bf16
  softmax_causal<<<dim3(S, B), blk, 0, stream>>>(Sc, P, am, S);
  // O_b = P_b · vT_b^T  (async-staged bf16 GEMM)
  gemm_nt_bf16<<<dim3(16, 8, 4), blk, 0, stream>>>(
      P, vT, out, S, D, S, 1.0f,
      (long)S * S, (long)D * S, (long)S * D);
}

// Round 3
// 386.123 us; speedup vs baseline: 1.1115x; 1.0492x over previous
//
#include <hip/hip_runtime.h>
#include <hip/hip_bf16.h>

typedef __bf16 bf16x8 __attribute__((ext_vector_type(8)));
typedef float floatx4 __attribute__((ext_vector_type(4)));
typedef unsigned short ushort_t;

// ---- 8-element fp32 load -> bf16x8 ----
__device__ __forceinline__ bf16x8 load8f(const float* p) {
  const float4* q = reinterpret_cast<const float4*>(p);
  float4 x = q[0], y = q[1];
  bf16x8 r;
  r[0] = (__bf16)x.x; r[1] = (__bf16)x.y; r[2] = (__bf16)x.z; r[3] = (__bf16)x.w;
  r[4] = (__bf16)y.x; r[5] = (__bf16)y.y; r[6] = (__bf16)y.z; r[7] = (__bf16)y.w;
  return r;
}

// ---- epilogue stores ----
__device__ __forceinline__ void storeC(float* C, long idx, float v) { C[idx] = v; }
__device__ __forceinline__ void storeC(ushort_t* C, long idx, float v) {
  __bf16 b = (__bf16)v;
  C[idx] = __builtin_bit_cast(ushort_t, b);
}

// async global->LDS, 16B per lane (m97 path)
__device__ __forceinline__ void glds16(const ushort_t* g, ushort_t* l) {
  __builtin_amdgcn_global_load_lds(
      (const __attribute__((address_space(1))) void*)g,
      (__attribute__((address_space(3))) void*)l, 16, 0, 0);
}

// =====================================================================
// Streaming fp32 -> bf16 convert. n must be a multiple of 2048.
// =====================================================================
__global__ __launch_bounds__(256) void f32_to_bf16(
    const float* __restrict__ src, ushort_t* __restrict__ dst, long n)
{
  const long i = (((long)blockIdx.x * 256) + threadIdx.x) * 8;
  if (i < n) {
    bf16x8 v = load8f(src + i);
    *reinterpret_cast<bf16x8*>(dst + i) = v;
  }
}

// =====================================================================
// All-bf16 NT GEMM, async global_load_lds (width 16) staging — m97
// structure. Unpadded LDS (64 B rows) as required by the wave-uniform
// base + lane*16 DMA addressing.
// C[m,n] = alpha * sum_k A[m,k]*B[n,k] (+ bias)
// BIAS_MODE: 0 = none, 1 = bias[n], 2 = bias[m]
// M % 128 == 0, N % 128 == 0, K % 32 == 0.
// =====================================================================
template<typename TC, int BIAS_MODE>
__global__ __launch_bounds__(256) void gemm_nt_bf16(
    const ushort_t* __restrict__ A, const ushort_t* __restrict__ B,
    const float* __restrict__ bias, TC* __restrict__ C,
    int M, int N, int K, float alpha,
    long sAb, long sBb, long sCb)
{
  __shared__ ushort_t As[128 * 32];   // 8 KB, unpadded
  __shared__ ushort_t Bs[128 * 32];

  const int bz = blockIdx.z;
  A += (long)bz * sAb;
  B += (long)bz * sBb;
  C += (long)bz * sCb;

  const int bm = blockIdx.x, bn = blockIdx.y;
  const int tid = threadIdx.x;
  const int wave = tid >> 6, lane = tid & 63;
  const int wm = (wave & 1) * 64, wn = (wave >> 1) * 64;
  const int lr = lane & 15, lq = lane >> 4;

  const ushort_t* Ab = A + (long)(bm * 128) * K;
  const ushort_t* Bb = B + (long)(bn * 128) * K;

  // staging segments: seg = t*256 + tid; row = seg>>2; elem off = (seg&3)*8
  const int seg0 = tid, seg1 = 256 + tid;
  const int sr0 = seg0 >> 2, sk0 = (seg0 & 3) << 3;
  const int sr1 = seg1 >> 2, sk1 = (seg1 & 3) << 3;

  floatx4 acc[4][4];
  #pragma unroll
  for (int i = 0; i < 4; ++i)
    #pragma unroll
    for (int j = 0; j < 4; ++j)
      acc[i][j] = (floatx4){0.f, 0.f, 0.f, 0.f};

  int aoff[4], boff[4];
  #pragma unroll
  for (int i = 0; i < 4; ++i) {
    aoff[i] = (wm + i * 16 + lr) * 32 + lq * 8;
    boff[i] = (wn + i * 16 + lr) * 32 + lq * 8;
  }

  const int ktiles = K >> 5;
  for (int kt = 0; kt < ktiles; ++kt) {
    const int kc = kt << 5;
    glds16(Ab + (long)sr0 * K + kc + sk0, &As[seg0 * 8]);
    glds16(Ab + (long)sr1 * K + kc + sk1, &As[seg1 * 8]);
    glds16(Bb + (long)sr0 * K + kc + sk0, &Bs[seg0 * 8]);
    glds16(Bb + (long)sr1 * K + kc + sk1, &Bs[seg1 * 8]);
    __syncthreads();   // compiler drains vmcnt(0) here

    bf16x8 af[4], bfr[4];
    #pragma unroll
    for (int i = 0; i < 4; ++i)
      af[i] = *reinterpret_cast<const bf16x8*>(&As[aoff[i]]);
    #pragma unroll
    for (int j = 0; j < 4; ++j)
      bfr[j] = *reinterpret_cast<const bf16x8*>(&Bs[boff[j]]);
    #pragma unroll
    for (int i = 0; i < 4; ++i)
      #pragma unroll
      for (int j = 0; j < 4; ++j)
        acc[i][j] = __builtin_amdgcn_mfma_f32_16x16x32_bf16(af[i], bfr[j], acc[i][j], 0, 0, 0);
    __syncthreads();
  }

  // epilogue: C/D layout col=lane&15, row=quad*4+reg (m89-verified)
  #pragma unroll
  for (int i = 0; i < 4; ++i) {
    #pragma unroll
    for (int j = 0; j < 4; ++j) {
      const int row0 = bm * 128 + wm + i * 16 + lq * 4;
      const int col  = bn * 128 + wn + j * 16 + lr;
      #pragma unroll
      for (int r = 0; r < 4; ++r) {
        float v = acc[i][j][r] * alpha;
        if (BIAS_MODE == 1) v += bias[col];
        if (BIAS_MODE == 2) v += bias[row0 + r];
        storeC(C, (long)(row0 + r) * N + col, v);
      }
    }
  }
}

// =====================================================================
// Row softmax, exact reference mask ordering; reads fp32 Sc, writes bf16 P.
//   v = s[j]; if (mask[b,j]==0) v = -1e10; if (j>i) v += -1e10; softmax.
// =====================================================================
__global__ __launch_bounds__(256) void softmax_causal(
    const float* __restrict__ Sc, ushort_t* __restrict__ P,
    const int* __restrict__ mask, int S)
{
  const int i = blockIdx.x, b = blockIdx.y;
  const float* row = Sc + ((long)b * S + i) * S;
  ushort_t* prow = P + ((long)b * S + i) * S;
  const int* mrow = mask + (long)b * S;
  const int tid = threadIdx.x;
  const int lane = tid & 63, wave = tid >> 6;
  __shared__ float red[4];

  float vals[8];
  float mymax = -3.4e38f;
  #pragma unroll
  for (int u = 0; u < 8; ++u) {
    const int j = tid + (u << 8);
    float v = row[j];
    if (mrow[j] == 0) v = -1e10f;
    if (j > i) v += -1e10f;
    vals[u] = v;
    mymax = fmaxf(mymax, v);
  }
  #pragma unroll
  for (int off = 32; off; off >>= 1)
    mymax = fmaxf(mymax, __shfl_xor(mymax, off));
  if (lane == 0) red[wave] = mymax;
  __syncthreads();
  const float m = fmaxf(fmaxf(red[0], red[1]), fmaxf(red[2], red[3]));
  __syncthreads();

  float sum = 0.f;
  #pragma unroll
  for (int u = 0; u < 8; ++u) {
    const float e = __expf(vals[u] - m);
    vals[u] = e;
    sum += e;
  }
  #pragma unroll
  for (int off = 32; off; off >>= 1)
    sum += __shfl_xor(sum, off);
  if (lane == 0) red[wave] = sum;
  __syncthreads();
  const float tot = red[0] + red[1] + red[2] + red[3];
  const float inv = 1.0f / tot;
  #pragma unroll
  for (int u = 0; u < 8; ++u) {
    const int j = tid + (u << 8);
    __bf16 bv = (__bf16)(vals[u] * inv);
    prow[j] = __builtin_bit_cast(ushort_t, bv);
  }
}

extern "C" void kernel_launch(void* const* d_in, const int* in_sizes, int n_in,
                              void* d_out, int out_size, void* d_ws, size_t ws_size,
                              hipStream_t stream)
{
  const int B = 4, S = 2048, D = 1024;
  const float* Q  = (const float*)d_in[0];
  const float* K  = (const float*)d_in[1];
  const float* V  = (const float*)d_in[2];
  const int*   am = (const int*)d_in[3];
  const float* Wq = (const float*)d_in[4];
  const float* bq = (const float*)d_in[5];
  const float* Wk = (const float*)d_in[6];
  const float* bk = (const float*)d_in[7];
  const float* Wv = (const float*)d_in[8];
  const float* bv = (const float*)d_in[9];
  float* out = (float*)d_out;

  const long MS = (long)B * S;                 // 8192 rows
  const long NQ = MS * D;                      // 8,388,608 elems
  const long NW = (long)D * D;                 // 1,048,576 elems

  // ws layout (112 MB total):
  //   [qb 16MB][kb 16MB][vT 16MB][Sc 64MB fp32]
  // Converted-input buffers alias the Sc region (dead until scores GEMM):
  //   Qb=Sc+0, Kb=+16MB, Vb=+32MB, Wqb=+48MB, Wkb=+50MB, Wvb=+52MB  (54<=64MB)
  // P (32MB bf16) aliases qb+kb (dead after scores GEMM).
  ushort_t* qb = (ushort_t*)d_ws;
  ushort_t* kb = qb + NQ;
  ushort_t* vT = kb + NQ;                      // [B][D][S]
  float*    Sc = (float*)(vT + NQ);            // [B][S][S]
  ushort_t* P  = qb;                           // [B][S][S] bf16, aliased

  ushort_t* Qb  = (ushort_t*)Sc;
  ushort_t* Kb  = Qb + NQ;
  ushort_t* Vb  = Kb + NQ;
  ushort_t* Wqb = Vb + NQ;
  ushort_t* Wkb = Wqb + NW;
  ushort_t* Wvb = Wkb + NW;

  dim3 blk(256);

  // ---- convert fp32 inputs to bf16 (HBM-bound streaming) ----
  f32_to_bf16<<<dim3((int)(NQ / 2048)), blk, 0, stream>>>(Q, Qb, NQ);
  f32_to_bf16<<<dim3((int)(NQ / 2048)), blk, 0, stream>>>(K, Kb, NQ);
  f32_to_bf16<<<dim3((int)(NQ / 2048)), blk, 0, stream>>>(V, Vb, NQ);
  f32_to_bf16<<<dim3((int)(NW / 2048)), blk, 0, stream>>>(Wq, Wqb, NW);
  f32_to_bf16<<<dim3((int)(NW / 2048)), blk, 0, stream>>>(Wk, Wkb, NW);
  f32_to_bf16<<<dim3((int)(NW / 2048)), blk, 0, stream>>>(Wv, Wvb, NW);

  // ---- projections (all async-staged bf16 GEMMs) ----
  // q = Q·Wq^T + bq
  gemm_nt_bf16<ushort_t, 1><<<dim3(64, 8, 1), blk, 0, stream>>>(
      Qb, Wqb, bq, qb, (int)MS, D, D, 1.0f, 0L, 0L, 0L);
  // k = K·Wk^T + bk
  gemm_nt_bf16<ushort_t, 1><<<dim3(64, 8, 1), blk, 0, stream>>>(
      Kb, Wkb, bk, kb, (int)MS, D, D, 1.0f, 0L, 0L, 0L);
  // vT[b,e,s] = sum_d Wv[e,d]*V[b,s,d] + bv[e]
  gemm_nt_bf16<ushort_t, 2><<<dim3(8, 16, 4), blk, 0, stream>>>(
      Wvb, Vb, bv, vT, D, S, D, 1.0f, 0L, (long)S * D, (long)D * S);

  // ---- attention ----
  // Sc_b = q_b · k_b^T / sqrt(D)
  gemm_nt_bf16<float, 0><<<dim3(16, 16, 4), blk, 0, stream>>>(
      qb, kb, nullptr, Sc, S, S, D, 0.03125f,
      (long)S * D, (long)S * D, (long)S * S);
  // softmax (mask + causal, reference ordering), P in bf16
  softmax_causal<<<dim3(S, B), blk, 0, stream>>>(Sc, P, am, S);
  // O_b = P_b · vT_b^T
  gemm_nt_bf16<float, 0><<<dim3(16, 8, 4), blk, 0, stream>>>(
      P, vT, nullptr, out, S, D, S, 1.0f,
      (long)S * S, (long)D * S, (long)S * D);
}

// Round 4
// 376.467 us; speedup vs baseline: 1.1400x; 1.0256x over previous
//
#include <hip/hip_runtime.h>
#include <hip/hip_bf16.h>

typedef __bf16 bf16x8 __attribute__((ext_vector_type(8)));
typedef float floatx4 __attribute__((ext_vector_type(4)));
typedef unsigned short ushort_t;

// ---- 8-element fp32 load -> bf16x8 ----
__device__ __forceinline__ bf16x8 load8f(const float* p) {
  const float4* q = reinterpret_cast<const float4*>(p);
  float4 x = q[0], y = q[1];
  bf16x8 r;
  r[0] = (__bf16)x.x; r[1] = (__bf16)x.y; r[2] = (__bf16)x.z; r[3] = (__bf16)x.w;
  r[4] = (__bf16)y.x; r[5] = (__bf16)y.y; r[6] = (__bf16)y.z; r[7] = (__bf16)y.w;
  return r;
}

// ---- epilogue stores ----
__device__ __forceinline__ void storeC(float* C, long idx, float v) { C[idx] = v; }
__device__ __forceinline__ void storeC(ushort_t* C, long idx, float v) {
  __bf16 b = (__bf16)v;
  C[idx] = __builtin_bit_cast(ushort_t, b);
}

// async global->LDS, 16B per lane (m97 path)
__device__ __forceinline__ void glds16(const ushort_t* g, ushort_t* l) {
  __builtin_amdgcn_global_load_lds(
      (const __attribute__((address_space(1))) void*)g,
      (__attribute__((address_space(3))) void*)l, 16, 0, 0);
}

// =====================================================================
// Batched fp32 -> bf16 convert: blockIdx.y selects among 3 sources;
// destinations are contiguous (dst + y*n). n % 2048 == 0.
// =====================================================================
__global__ __launch_bounds__(256) void cvt3(
    const float* __restrict__ s0, const float* __restrict__ s1,
    const float* __restrict__ s2, ushort_t* __restrict__ dst, long n)
{
  const int z = blockIdx.y;
  const float* s = (z == 0) ? s0 : ((z == 1) ? s1 : s2);
  ushort_t* d = dst + (long)z * n;
  const long i = (((long)blockIdx.x * 256) + threadIdx.x) * 8;
  if (i < n) {
    bf16x8 v = load8f(s + i);
    *reinterpret_cast<bf16x8*>(d + i) = v;
  }
}

// =====================================================================
// j0[b] = first key index with mask[b,j] != 0 (S if none).
// Rows i < j0 have a fully-masked prefix -> their upper-triangle scores
// matter; all other rows' upper triangle is annihilated by the causal
// -1e10 in softmax regardless of stored value.
// =====================================================================
__global__ __launch_bounds__(256) void find_j0(
    const int* __restrict__ mask, int* __restrict__ j0, int S)
{
  const int b = blockIdx.x;
  const int* m = mask + (long)b * S;
  const int tid = threadIdx.x;
  int best = S;
  for (int j = tid; j < S; j += 256)
    if (m[j] != 0) best = min(best, j);
  #pragma unroll
  for (int off = 32; off; off >>= 1)
    best = min(best, __shfl_xor(best, off));
  __shared__ int red[4];
  if ((tid & 63) == 0) red[tid >> 6] = best;
  __syncthreads();
  if (tid == 0) j0[b] = min(min(red[0], red[1]), min(red[2], red[3]));
}

// =====================================================================
// All-bf16 NT GEMM, async global_load_lds (width 16) staging (m97).
// C[m,n] = alpha * sum_k A[m,k]*B[n,k] (+ bias)
// BIAS_MODE: 0=none, 1=bias[n] (bias_b used for bz==1 if non-null),
//            2=bias[m]
// CSKIP: skip strictly-upper 128x128 tiles unless a row in the tile has
//        a fully-masked key prefix (i < j0[bz]).
// M,N % 128 == 0; K % 32 == 0.
// =====================================================================
template<typename TC, int BIAS_MODE, bool CSKIP>
__global__ __launch_bounds__(256) void gemm_nt_bf16(
    const ushort_t* __restrict__ A, const ushort_t* __restrict__ B,
    const float* __restrict__ bias, const float* __restrict__ bias_b,
    TC* __restrict__ C, const int* __restrict__ j0p,
    int M, int N, int K, float alpha,
    long sAb, long sBb, long sCb)
{
  const int bz = blockIdx.z;
  const int bm = blockIdx.x, bn = blockIdx.y;

  if (CSKIP) {
    // strictly-upper tile: needed only if some row i in [bm*128, ..] has
    // i < j0[bz]  <=>  bm*128 < j0[bz]
    if (bn > bm && j0p[bz] <= bm * 128) return;
  }

  __shared__ ushort_t As[128 * 32];   // 8 KB, unpadded (DMA layout)
  __shared__ ushort_t Bs[128 * 32];

  A += (long)bz * sAb;
  B += (long)bz * sBb;
  C += (long)bz * sCb;
  if (BIAS_MODE == 1 && bz == 1 && bias_b) bias = bias_b;

  const int tid = threadIdx.x;
  const int wave = tid >> 6, lane = tid & 63;
  const int wm = (wave & 1) * 64, wn = (wave >> 1) * 64;
  const int lr = lane & 15, lq = lane >> 4;

  const ushort_t* Ab = A + (long)(bm * 128) * K;
  const ushort_t* Bb = B + (long)(bn * 128) * K;

  const int seg0 = tid, seg1 = 256 + tid;
  const int sr0 = seg0 >> 2, sk0 = (seg0 & 3) << 3;
  const int sr1 = seg1 >> 2, sk1 = (seg1 & 3) << 3;

  floatx4 acc[4][4];
  #pragma unroll
  for (int i = 0; i < 4; ++i)
    #pragma unroll
    for (int j = 0; j < 4; ++j)
      acc[i][j] = (floatx4){0.f, 0.f, 0.f, 0.f};

  int aoff[4], boff[4];
  #pragma unroll
  for (int i = 0; i < 4; ++i) {
    aoff[i] = (wm + i * 16 + lr) * 32 + lq * 8;
    boff[i] = (wn + i * 16 + lr) * 32 + lq * 8;
  }

  const int ktiles = K >> 5;
  for (int kt = 0; kt < ktiles; ++kt) {
    const int kc = kt << 5;
    glds16(Ab + (long)sr0 * K + kc + sk0, &As[seg0 * 8]);
    glds16(Ab + (long)sr1 * K + kc + sk1, &As[seg1 * 8]);
    glds16(Bb + (long)sr0 * K + kc + sk0, &Bs[seg0 * 8]);
    glds16(Bb + (long)sr1 * K + kc + sk1, &Bs[seg1 * 8]);
    __syncthreads();

    bf16x8 af[4], bfr[4];
    #pragma unroll
    for (int i = 0; i < 4; ++i)
      af[i] = *reinterpret_cast<const bf16x8*>(&As[aoff[i]]);
    #pragma unroll
    for (int j = 0; j < 4; ++j)
      bfr[j] = *reinterpret_cast<const bf16x8*>(&Bs[boff[j]]);
    #pragma unroll
    for (int i = 0; i < 4; ++i)
      #pragma unroll
      for (int j = 0; j < 4; ++j)
        acc[i][j] = __builtin_amdgcn_mfma_f32_16x16x32_bf16(af[i], bfr[j], acc[i][j], 0, 0, 0);
    __syncthreads();
  }

  // epilogue: C/D layout col=lane&15, row=quad*4+reg (m89-verified)
  #pragma unroll
  for (int i = 0; i < 4; ++i) {
    #pragma unroll
    for (int j = 0; j < 4; ++j) {
      const int row0 = bm * 128 + wm + i * 16 + lq * 4;
      const int col  = bn * 128 + wn + j * 16 + lr;
      #pragma unroll
      for (int r = 0; r < 4; ++r) {
        float v = acc[i][j][r] * alpha;
        if (BIAS_MODE == 1) v += bias[col];
        if (BIAS_MODE == 2) v += bias[row0 + r];
        storeC(C, (long)(row0 + r) * N + col, v);
      }
    }
  }
}

// =====================================================================
// Row softmax, exact reference ordering; bf16 Sc in, bf16 P out.
//   v = s[j]; if (mask[b,j]==0) v=-1e10; if (j>i) v += -1e10; softmax.
// Each thread owns 8 consecutive elements (vectorized 16B loads/stores).
// =====================================================================
__global__ __launch_bounds__(256) void softmax_causal(
    const ushort_t* __restrict__ Sc, ushort_t* __restrict__ P,
    const int* __restrict__ mask, int S)
{
  const int i = blockIdx.x, b = blockIdx.y;
  const ushort_t* row = Sc + ((long)b * S + i) * S;
  ushort_t* prow = P + ((long)b * S + i) * S;
  const int* mrow = mask + (long)b * S;
  const int tid = threadIdx.x;
  const int lane = tid & 63, wave = tid >> 6;
  const int j0 = tid * 8;
  __shared__ float red[4];

  bf16x8 sv = *reinterpret_cast<const bf16x8*>(row + j0);
  const int4* mp = reinterpret_cast<const int4*>(mrow + j0);
  int4 m0 = mp[0], m1 = mp[1];
  int mk[8] = {m0.x, m0.y, m0.z, m0.w, m1.x, m1.y, m1.z, m1.w};

  float vals[8];
  float mymax = -3.4e38f;
  #pragma unroll
  for (int u = 0; u < 8; ++u) {
    const int j = j0 + u;
    float v = (float)sv[u];
    if (mk[u] == 0) v = -1e10f;
    if (j > i) v += -1e10f;
    vals[u] = v;
    mymax = fmaxf(mymax, v);
  }
  #pragma unroll
  for (int off = 32; off; off >>= 1)
    mymax = fmaxf(mymax, __shfl_xor(mymax, off));
  if (lane == 0) red[wave] = mymax;
  __syncthreads();
  const float m = fmaxf(fmaxf(red[0], red[1]), fmaxf(red[2], red[3]));
  __syncthreads();

  float sum = 0.f;
  #pragma unroll
  for (int u = 0; u < 8; ++u) {
    const float e = __expf(vals[u] - m);
    vals[u] = e;
    sum += e;
  }
  #pragma unroll
  for (int off = 32; off; off >>= 1)
    sum += __shfl_xor(sum, off);
  if (lane == 0) red[wave] = sum;
  __syncthreads();
  const float tot = red[0] + red[1] + red[2] + red[3];
  const float inv = 1.0f / tot;

  bf16x8 pv;
  #pragma unroll
  for (int u = 0; u < 8; ++u) pv[u] = (__bf16)(vals[u] * inv);
  *reinterpret_cast<bf16x8*>(prow + j0) = pv;
}

extern "C" void kernel_launch(void* const* d_in, const int* in_sizes, int n_in,
                              void* d_out, int out_size, void* d_ws, size_t ws_size,
                              hipStream_t stream)
{
  const int B = 4, S = 2048, D = 1024;
  const float* Q  = (const float*)d_in[0];
  const float* K  = (const float*)d_in[1];
  const float* V  = (const float*)d_in[2];
  const int*   am = (const int*)d_in[3];
  const float* Wq = (const float*)d_in[4];
  const float* bq = (const float*)d_in[5];
  const float* Wk = (const float*)d_in[6];
  const float* bk = (const float*)d_in[7];
  const float* Wv = (const float*)d_in[8];
  const float* bv = (const float*)d_in[9];
  float* out = (float*)d_out;

  const long MS = (long)B * S;       // 8192
  const long NQ = MS * D;            // 8.39M elems (16 MB bf16)
  const long NW = (long)D * D;       // 1.05M elems (2 MB bf16)
  const long NS = (long)B * S * S;   // 16.8M elems (32 MB bf16)

  // ws byte layout (102 MB + j0):
  //  [0,16)   qb      [16,32) kb      [32,48) vT
  //  [48,64)  Qb      [64,80) Kb      [80,96) Vb
  //  [96,102) Wqb,Wkb,Wvb (contiguous)
  //  [102,+16B) j0
  // Aliases (ordering-safe, sequential stream):
  //  Sc(bf16, 32MB) = [48,80)  — written after Qb/Kb dead
  //  P (bf16, 32MB) = [0,32)   — written after qb/kb dead
  ushort_t* qb = (ushort_t*)d_ws;
  ushort_t* kb = qb + NQ;
  ushort_t* vT = kb + NQ;
  ushort_t* Qb = vT + NQ;            // convert dst (Q,K,V contiguous)
  ushort_t* Wqb = Qb + 3 * NQ;       // weights contiguous
  int* j0 = (int*)(Wqb + 3 * NW);
  ushort_t* Sc = Qb;                 // alias
  ushort_t* P  = qb;                 // alias

  dim3 blk(256);

  // ---- converts (2 dispatches) + j0 scan ----
  cvt3<<<dim3((int)(NQ / 2048), 3), blk, 0, stream>>>(Q, K, V, Qb, NQ);
  cvt3<<<dim3((int)(NW / 2048), 3), blk, 0, stream>>>(Wq, Wk, Wv, Wqb, NW);
  find_j0<<<dim3(B), blk, 0, stream>>>(am, j0, S);

  // ---- projections ----
  // merged q & k: z=0 -> q = Q·Wq^T + bq ; z=1 -> k = K·Wk^T + bk
  gemm_nt_bf16<ushort_t, 1, false><<<dim3(64, 8, 2), blk, 0, stream>>>(
      Qb, Wqb, bq, bk, qb, nullptr, (int)MS, D, D, 1.0f, NQ, NW, NQ);
  // vT[b,e,s] = sum_d Wv[e,d]*V[b,s,d] + bv[e]
  gemm_nt_bf16<ushort_t, 2, false><<<dim3(8, 16, 4), blk, 0, stream>>>(
      Wqb + 2 * NW, Qb + 2 * NQ, bv, nullptr, vT, nullptr,
      D, S, D, 1.0f, 0L, (long)S * D, (long)D * S);

  // ---- attention ----
  // Sc_b = q_b · k_b^T / sqrt(D), bf16 out, mask-safe causal tile skip
  gemm_nt_bf16<ushort_t, 0, true><<<dim3(16, 16, 4), blk, 0, stream>>>(
      qb, kb, nullptr, nullptr, Sc, j0, S, S, D, 0.03125f,
      (long)S * D, (long)S * D, (long)S * S);
  // softmax (mask + causal, reference ordering)
  softmax_causal<<<dim3(S, B), blk, 0, stream>>>(Sc, P, am, S);
  // O_b = P_b · vT_b^T
  gemm_nt_bf16<float, 0, false><<<dim3(16, 8, 4), blk, 0, stream>>>(
      P, vT, nullptr, nullptr, out, nullptr, S, D, S, 1.0f,
      (long)S * S, (long)D * S, (long)S * D);
}

// Round 5
// 353.847 us; speedup vs baseline: 1.2129x; 1.0639x over previous
//
#include <hip/hip_runtime.h>
#include <hip/hip_bf16.h>

typedef __bf16 bf16x8 __attribute__((ext_vector_type(8)));
typedef float floatx4 __attribute__((ext_vector_type(4)));
typedef unsigned short ushort_t;

// ---- 8-element fp32 load -> bf16x8 ----
__device__ __forceinline__ bf16x8 load8f(const float* p) {
  const float4* q = reinterpret_cast<const float4*>(p);
  float4 x = q[0], y = q[1];
  bf16x8 r;
  r[0] = (__bf16)x.x; r[1] = (__bf16)x.y; r[2] = (__bf16)x.z; r[3] = (__bf16)x.w;
  r[4] = (__bf16)y.x; r[5] = (__bf16)y.y; r[6] = (__bf16)y.z; r[7] = (__bf16)y.w;
  return r;
}

// ---- epilogue stores ----
__device__ __forceinline__ void storeC(float* C, long idx, float v) { C[idx] = v; }
__device__ __forceinline__ void storeC(ushort_t* C, long idx, float v) {
  __bf16 b = (__bf16)v;
  C[idx] = __builtin_bit_cast(ushort_t, b);
}

// async global->LDS, 16B per lane
__device__ __forceinline__ void glds16(const ushort_t* g, ushort_t* l) {
  __builtin_amdgcn_global_load_lds(
      (const __attribute__((address_space(1))) void*)g,
      (__attribute__((address_space(3))) void*)l, 16, 0, 0);
}

// =====================================================================
// Batched fp32 -> bf16 convert (3 sources via blockIdx.y, contiguous
// dsts). Optionally folds the mask j0 scan into blocks (y==0, x<B):
// j0[b] = first key index with mask[b,j]!=0 (S if none).
// =====================================================================
__global__ __launch_bounds__(256) void cvt3(
    const float* __restrict__ s0, const float* __restrict__ s1,
    const float* __restrict__ s2, ushort_t* __restrict__ dst, long n,
    const int* __restrict__ mask, int* __restrict__ j0, int S, int B)
{
  const int z = blockIdx.y;
  const float* s = (z == 0) ? s0 : ((z == 1) ? s1 : s2);
  ushort_t* d = dst + (long)z * n;
  const long i = (((long)blockIdx.x * 256) + threadIdx.x) * 8;
  if (i < n) {
    bf16x8 v = load8f(s + i);
    *reinterpret_cast<bf16x8*>(d + i) = v;
  }
  if (mask && z == 0 && (int)blockIdx.x < B) {
    const int b = blockIdx.x;
    const int* m = mask + (long)b * S;
    const int tid = threadIdx.x;
    int best = S;
    for (int j = tid; j < S; j += 256)
      if (m[j] != 0) best = min(best, j);
    #pragma unroll
    for (int off = 32; off; off >>= 1)
      best = min(best, __shfl_xor(best, off));
    __shared__ int red[4];
    if ((tid & 63) == 0) red[tid >> 6] = best;
    __syncthreads();
    if (tid == 0) j0[b] = min(min(red[0], red[1]), min(red[2], red[3]));
  }
}

// =====================================================================
// All-bf16 NT GEMM, async global_load_lds staging with DOUBLE-BUFFERED
// LDS: one barrier per K-iter; the prefetch DMA for tile k+1 is issued
// right after the barrier and flies under tile k's ds_read+MFMA phase,
// so the next barrier's vmcnt(0) drain finds it (mostly) landed.
// C[m,n] = alpha * sum_k A[m,k]*B[n,k] (+ bias)
// BIAS_MODE: 0=none, 1=bias[n] (bias_b for bz==1 if non-null), 2=bias[m]
// CSKIP: skip strictly-upper 128x128 tiles unless a row has a fully
//        masked key prefix (bm*128 < j0[bz]).
// M,N % 128 == 0; K % 32 == 0.
// =====================================================================
template<typename TC, int BIAS_MODE, bool CSKIP>
__global__ __launch_bounds__(256) void gemm_nt_bf16(
    const ushort_t* __restrict__ A, const ushort_t* __restrict__ B,
    const float* __restrict__ bias, const float* __restrict__ bias_b,
    TC* __restrict__ C, const int* __restrict__ j0p,
    int M, int N, int K, float alpha,
    long sAb, long sBb, long sCb)
{
  const int bz = blockIdx.z;
  const int bm = blockIdx.x, bn = blockIdx.y;

  if (CSKIP) {
    if (bn > bm && j0p[bz] <= bm * 128) return;
  }

  __shared__ ushort_t As[2][128 * 32];   // 2 x 8 KB
  __shared__ ushort_t Bs[2][128 * 32];

  A += (long)bz * sAb;
  B += (long)bz * sBb;
  C += (long)bz * sCb;
  if (BIAS_MODE == 1 && bz == 1 && bias_b) bias = bias_b;

  const int tid = threadIdx.x;
  const int wave = tid >> 6, lane = tid & 63;
  const int wm = (wave & 1) * 64, wn = (wave >> 1) * 64;
  const int lr = lane & 15, lq = lane >> 4;

  const ushort_t* Ab = A + (long)(bm * 128) * K;
  const ushort_t* Bb = B + (long)(bn * 128) * K;

  const int seg0 = tid, seg1 = 256 + tid;
  const int sr0 = seg0 >> 2, sk0 = (seg0 & 3) << 3;
  const int sr1 = seg1 >> 2, sk1 = (seg1 & 3) << 3;

  const ushort_t* a0 = Ab + (long)sr0 * K + sk0;
  const ushort_t* a1 = Ab + (long)sr1 * K + sk1;
  const ushort_t* b0 = Bb + (long)sr0 * K + sk0;
  const ushort_t* b1 = Bb + (long)sr1 * K + sk1;
  const int l0 = seg0 * 8, l1 = seg1 * 8;

  floatx4 acc[4][4];
  #pragma unroll
  for (int i = 0; i < 4; ++i)
    #pragma unroll
    for (int j = 0; j < 4; ++j)
      acc[i][j] = (floatx4){0.f, 0.f, 0.f, 0.f};

  int aoff[4], boff[4];
  #pragma unroll
  for (int i = 0; i < 4; ++i) {
    aoff[i] = (wm + i * 16 + lr) * 32 + lq * 8;
    boff[i] = (wn + i * 16 + lr) * 32 + lq * 8;
  }

  // prologue: stage K-tile 0 into buffer 0
  glds16(a0, &As[0][l0]);
  glds16(a1, &As[0][l1]);
  glds16(b0, &Bs[0][l0]);
  glds16(b1, &Bs[0][l1]);

  const int ktiles = K >> 5;
  for (int kt = 0; kt < ktiles; ++kt) {
    const int cur = kt & 1;
    __syncthreads();            // drains buf[cur] DMA; frees buf[cur^1]
    if (kt + 1 < ktiles) {
      const int kc = (kt + 1) << 5;
      const int nxt = cur ^ 1;
      glds16(a0 + kc, &As[nxt][l0]);
      glds16(a1 + kc, &As[nxt][l1]);
      glds16(b0 + kc, &Bs[nxt][l0]);
      glds16(b1 + kc, &Bs[nxt][l1]);
    }
    bf16x8 af[4], bfr[4];
    #pragma unroll
    for (int i = 0; i < 4; ++i)
      af[i] = *reinterpret_cast<const bf16x8*>(&As[cur][aoff[i]]);
    #pragma unroll
    for (int j = 0; j < 4; ++j)
      bfr[j] = *reinterpret_cast<const bf16x8*>(&Bs[cur][boff[j]]);
    #pragma unroll
    for (int i = 0; i < 4; ++i)
      #pragma unroll
      for (int j = 0; j < 4; ++j)
        acc[i][j] = __builtin_amdgcn_mfma_f32_16x16x32_bf16(af[i], bfr[j], acc[i][j], 0, 0, 0);
  }

  // epilogue: C/D layout col=lane&15, row=quad*4+reg (m89-verified)
  #pragma unroll
  for (int i = 0; i < 4; ++i) {
    #pragma unroll
    for (int j = 0; j < 4; ++j) {
      const int row0 = bm * 128 + wm + i * 16 + lq * 4;
      const int col  = bn * 128 + wn + j * 16 + lr;
      #pragma unroll
      for (int r = 0; r < 4; ++r) {
        float v = acc[i][j][r] * alpha;
        if (BIAS_MODE == 1) v += bias[col];
        if (BIAS_MODE == 2) v += bias[row0 + r];
        storeC(C, (long)(row0 + r) * N + col, v);
      }
    }
  }
}

// =====================================================================
// Row softmax, exact reference ordering; bf16 Sc in, bf16 P out.
//   v = s[j]; if (mask[b,j]==0) v=-1e10; if (j>i) v += -1e10; softmax.
// =====================================================================
__global__ __launch_bounds__(256) void softmax_causal(
    const ushort_t* __restrict__ Sc, ushort_t* __restrict__ P,
    const int* __restrict__ mask, int S)
{
  const int i = blockIdx.x, b = blockIdx.y;
  const ushort_t* row = Sc + ((long)b * S + i) * S;
  ushort_t* prow = P + ((long)b * S + i) * S;
  const int* mrow = mask + (long)b * S;
  const int tid = threadIdx.x;
  const int lane = tid & 63, wave = tid >> 6;
  const int j0 = tid * 8;
  __shared__ float red[4];

  bf16x8 sv = *reinterpret_cast<const bf16x8*>(row + j0);
  const int4* mp = reinterpret_cast<const int4*>(mrow + j0);
  int4 m0 = mp[0], m1 = mp[1];
  int mk[8] = {m0.x, m0.y, m0.z, m0.w, m1.x, m1.y, m1.z, m1.w};

  float vals[8];
  float mymax = -3.4e38f;
  #pragma unroll
  for (int u = 0; u < 8; ++u) {
    const int j = j0 + u;
    float v = (float)sv[u];
    if (mk[u] == 0) v = -1e10f;
    if (j > i) v += -1e10f;
    vals[u] = v;
    mymax = fmaxf(mymax, v);
  }
  #pragma unroll
  for (int off = 32; off; off >>= 1)
    mymax = fmaxf(mymax, __shfl_xor(mymax, off));
  if (lane == 0) red[wave] = mymax;
  __syncthreads();
  const float m = fmaxf(fmaxf(red[0], red[1]), fmaxf(red[2], red[3]));
  __syncthreads();

  float sum = 0.f;
  #pragma unroll
  for (int u = 0; u < 8; ++u) {
    const float e = __expf(vals[u] - m);
    vals[u] = e;
    sum += e;
  }
  #pragma unroll
  for (int off = 32; off; off >>= 1)
    sum += __shfl_xor(sum, off);
  if (lane == 0) red[wave] = sum;
  __syncthreads();
  const float tot = red[0] + red[1] + red[2] + red[3];
  const float inv = 1.0f / tot;

  bf16x8 pv;
  #pragma unroll
  for (int u = 0; u < 8; ++u) pv[u] = (__bf16)(vals[u] * inv);
  *reinterpret_cast<bf16x8*>(prow + j0) = pv;
}

extern "C" void kernel_launch(void* const* d_in, const int* in_sizes, int n_in,
                              void* d_out, int out_size, void* d_ws, size_t ws_size,
                              hipStream_t stream)
{
  const int B = 4, S = 2048, D = 1024;
  const float* Q  = (const float*)d_in[0];
  const float* K  = (const float*)d_in[1];
  const float* V  = (const float*)d_in[2];
  const int*   am = (const int*)d_in[3];
  const float* Wq = (const float*)d_in[4];
  const float* bq = (const float*)d_in[5];
  const float* Wk = (const float*)d_in[6];
  const float* bk = (const float*)d_in[7];
  const float* Wv = (const float*)d_in[8];
  const float* bv = (const float*)d_in[9];
  float* out = (float*)d_out;

  const long MS = (long)B * S;       // 8192
  const long NQ = MS * D;            // 8.39M elems (16 MB bf16)
  const long NW = (long)D * D;       // 1.05M elems (2 MB bf16)

  // ws byte layout (102 MB + j0):
  //  [0,16) qb  [16,32) kb  [32,48) vT
  //  [48,64) Qb [64,80) Kb  [80,96) Vb
  //  [96,102) Wqb,Wkb,Wvb   [102,+16B) j0
  // Aliases (ordering-safe on the sequential stream):
  //  Sc(bf16,32MB) = [48,80)  (Qb/Kb dead after projections)
  //  P (bf16,32MB) = [0,32)   (qb/kb dead after scores GEMM)
  ushort_t* qb = (ushort_t*)d_ws;
  ushort_t* kb = qb + NQ;
  ushort_t* vT = kb + NQ;
  ushort_t* Qb = vT + NQ;
  ushort_t* Wqb = Qb + 3 * NQ;
  int* j0 = (int*)(Wqb + 3 * NW);
  ushort_t* Sc = Qb;                 // alias
  ushort_t* P  = qb;                 // alias

  dim3 blk(256);

  // converts (j0 scan folded into the first)
  cvt3<<<dim3((int)(NQ / 2048), 3), blk, 0, stream>>>(Q, K, V, Qb, NQ, am, j0, S, B);
  cvt3<<<dim3((int)(NW / 2048), 3), blk, 0, stream>>>(Wq, Wk, Wv, Wqb, NW,
                                                      nullptr, nullptr, S, B);

  // projections: z=0 -> q = Q·Wq^T+bq ; z=1 -> k = K·Wk^T+bk
  gemm_nt_bf16<ushort_t, 1, false><<<dim3(64, 8, 2), blk, 0, stream>>>(
      Qb, Wqb, bq, bk, qb, nullptr, (int)MS, D, D, 1.0f, NQ, NW, NQ);
  // vT[b,e,s] = sum_d Wv[e,d]*V[b,s,d] + bv[e]
  gemm_nt_bf16<ushort_t, 2, false><<<dim3(8, 16, 4), blk, 0, stream>>>(
      Wqb + 2 * NW, Qb + 2 * NQ, bv, nullptr, vT, nullptr,
      D, S, D, 1.0f, 0L, (long)S * D, (long)D * S);

  // Sc_b = q_b·k_b^T / sqrt(D), bf16 out, mask-safe causal tile skip
  gemm_nt_bf16<ushort_t, 0, true><<<dim3(16, 16, 4), blk, 0, stream>>>(
      qb, kb, nullptr, nullptr, Sc, j0, S, S, D, 0.03125f,
      (long)S * D, (long)S * D, (long)S * S);
  // softmax (mask + causal, reference ordering)
  softmax_causal<<<dim3(S, B), blk, 0, stream>>>(Sc, P, am, S);
  // O_b = P_b · vT_b^T
  gemm_nt_bf16<float, 0, false><<<dim3(16, 8, 4), blk, 0, stream>>>(
      P, vT, nullptr, nullptr, out, nullptr, S, D, S, 1.0f,
      (long)S * S, (long)D * S, (long)S * D);
}

// Round 6
// 353.773 us; speedup vs baseline: 1.2132x; 1.0002x over previous
//
#include <hip/hip_runtime.h>
#include <hip/hip_bf16.h>

typedef __bf16 bf16x8 __attribute__((ext_vector_type(8)));
typedef float floatx4 __attribute__((ext_vector_type(4)));
typedef unsigned short ushort_t;

// ---- 8-element fp32 load -> bf16x8 ----
__device__ __forceinline__ bf16x8 load8f(const float* p) {
  const float4* q = reinterpret_cast<const float4*>(p);
  float4 x = q[0], y = q[1];
  bf16x8 r;
  r[0] = (__bf16)x.x; r[1] = (__bf16)x.y; r[2] = (__bf16)x.z; r[3] = (__bf16)x.w;
  r[4] = (__bf16)y.x; r[5] = (__bf16)y.y; r[6] = (__bf16)y.z; r[7] = (__bf16)y.w;
  return r;
}

// ---- epilogue stores ----
__device__ __forceinline__ void storeC(float* C, long idx, float v) { C[idx] = v; }
__device__ __forceinline__ void storeC(ushort_t* C, long idx, float v) {
  __bf16 b = (__bf16)v;
  C[idx] = __builtin_bit_cast(ushort_t, b);
}

// async global->LDS, 16B per lane
__device__ __forceinline__ void glds16(const ushort_t* g, ushort_t* l) {
  __builtin_amdgcn_global_load_lds(
      (const __attribute__((address_space(1))) void*)g,
      (__attribute__((address_space(3))) void*)l, 16, 0, 0);
}

// fence-less barrier + fine-grained vm waits (m139-validated pattern).
// "memory" clobber pins compiler-level ordering; no vmcnt(0) drain emitted.
__device__ __forceinline__ void bar_raw()  { asm volatile("s_barrier" ::: "memory"); }
__device__ __forceinline__ void wait_vm4() { asm volatile("s_waitcnt vmcnt(4)" ::: "memory"); }
__device__ __forceinline__ void wait_vm0() { asm volatile("s_waitcnt vmcnt(0)" ::: "memory"); }

// =====================================================================
// Batched fp32 -> bf16 convert (3 sources via blockIdx.y, contiguous
// dsts). Folds the mask j0 scan into y==0, x<B blocks.
// =====================================================================
__global__ __launch_bounds__(256) void cvt3(
    const float* __restrict__ s0, const float* __restrict__ s1,
    const float* __restrict__ s2, ushort_t* __restrict__ dst, long n,
    const int* __restrict__ mask, int* __restrict__ j0, int S, int B)
{
  const int z = blockIdx.y;
  const float* s = (z == 0) ? s0 : ((z == 1) ? s1 : s2);
  ushort_t* d = dst + (long)z * n;
  const long i = (((long)blockIdx.x * 256) + threadIdx.x) * 8;
  if (i < n) {
    bf16x8 v = load8f(s + i);
    *reinterpret_cast<bf16x8*>(d + i) = v;
  }
  if (mask && z == 0 && (int)blockIdx.x < B) {
    const int b = blockIdx.x;
    const int* m = mask + (long)b * S;
    const int tid = threadIdx.x;
    int best = S;
    for (int j = tid; j < S; j += 256)
      if (m[j] != 0) best = min(best, j);
    #pragma unroll
    for (int off = 32; off; off >>= 1)
      best = min(best, __shfl_xor(best, off));
    __shared__ int red[4];
    if ((tid & 63) == 0) red[tid >> 6] = best;
    __syncthreads();
    if (tid == 0) j0[b] = min(min(red[0], red[1]), min(red[2], red[3]));
  }
}

// =====================================================================
// All-bf16 NT GEMM, 3-stage software pipeline over global_load_lds:
// prefetch distance 2, fine-grained s_waitcnt vmcnt(4) (waits only the
// oldest tile's 4 DMAs; the next tile's stay in flight) + fence-less
// s_barrier. Each tile's DMA gets ~2 compute phases to land.
// C[m,n] = alpha * sum_k A[m,k]*B[n,k] (+ bias)
// BIAS_MODE: 0=none, 1=bias[n] (bias_b for bz==1 if non-null), 2=bias[m]
// CSKIP: skip strictly-upper 128x128 tiles unless bm*128 < j0[bz].
// M,N % 128 == 0; K % 32 == 0; K/32 >= 2.
// =====================================================================
template<typename TC, int BIAS_MODE, bool CSKIP>
__global__ __launch_bounds__(256) void gemm_nt_bf16(
    const ushort_t* __restrict__ A, const ushort_t* __restrict__ B,
    const float* __restrict__ bias, const float* __restrict__ bias_b,
    TC* __restrict__ C, const int* __restrict__ j0p,
    int M, int N, int K, float alpha,
    long sAb, long sBb, long sCb)
{
  const int bz = blockIdx.z;
  const int bm = blockIdx.x, bn = blockIdx.y;

  if (CSKIP) {
    if (bn > bm && j0p[bz] <= bm * 128) return;
  }

  __shared__ ushort_t As[3][128 * 32];   // 3 x 8 KB
  __shared__ ushort_t Bs[3][128 * 32];

  A += (long)bz * sAb;
  B += (long)bz * sBb;
  C += (long)bz * sCb;
  if (BIAS_MODE == 1 && bz == 1 && bias_b) bias = bias_b;

  const int tid = threadIdx.x;
  const int wave = tid >> 6, lane = tid & 63;
  const int wm = (wave & 1) * 64, wn = (wave >> 1) * 64;
  const int lr = lane & 15, lq = lane >> 4;

  const ushort_t* Ab = A + (long)(bm * 128) * K;
  const ushort_t* Bb = B + (long)(bn * 128) * K;

  const int seg0 = tid, seg1 = 256 + tid;
  const int sr0 = seg0 >> 2, sk0 = (seg0 & 3) << 3;
  const int sr1 = seg1 >> 2, sk1 = (seg1 & 3) << 3;

  const ushort_t* a0 = Ab + (long)sr0 * K + sk0;
  const ushort_t* a1 = Ab + (long)sr1 * K + sk1;
  const ushort_t* b0 = Bb + (long)sr0 * K + sk0;
  const ushort_t* b1 = Bb + (long)sr1 * K + sk1;
  const int l0 = seg0 * 8, l1 = seg1 * 8;

  floatx4 acc[4][4];
  #pragma unroll
  for (int i = 0; i < 4; ++i)
    #pragma unroll
    for (int j = 0; j < 4; ++j)
      acc[i][j] = (floatx4){0.f, 0.f, 0.f, 0.f};

  int aoff[4], boff[4];
  #pragma unroll
  for (int i = 0; i < 4; ++i) {
    aoff[i] = (wm + i * 16 + lr) * 32 + lq * 8;
    boff[i] = (wn + i * 16 + lr) * 32 + lq * 8;
  }

  // prologue: stage tiles 0 and 1
  glds16(a0, &As[0][l0]);
  glds16(a1, &As[0][l1]);
  glds16(b0, &Bs[0][l0]);
  glds16(b1, &Bs[0][l1]);
  glds16(a0 + 32, &As[1][l0]);
  glds16(a1 + 32, &As[1][l1]);
  glds16(b0 + 32, &Bs[1][l0]);
  glds16(b1 + 32, &Bs[1][l1]);

  const int ktiles = K >> 5;
  int cur = 0, nxt2 = 2;     // buffer of tile kt, buffer of tile kt+2
  for (int kt = 0; kt < ktiles; ++kt) {
    // wait ONLY the oldest in-flight tile (4 DMAs); keep the next in flight
    if (kt + 1 < ktiles) wait_vm4(); else wait_vm0();
    bar_raw();               // all waves' tile-kt DMAs drained; buf[nxt2] free
    if (kt + 2 < ktiles) {
      const int kc = (kt + 2) << 5;
      glds16(a0 + kc, &As[nxt2][l0]);
      glds16(a1 + kc, &As[nxt2][l1]);
      glds16(b0 + kc, &Bs[nxt2][l0]);
      glds16(b1 + kc, &Bs[nxt2][l1]);
    }
    bf16x8 af[4], bfr[4];
    #pragma unroll
    for (int i = 0; i < 4; ++i)
      af[i] = *reinterpret_cast<const bf16x8*>(&As[cur][aoff[i]]);
    #pragma unroll
    for (int j = 0; j < 4; ++j)
      bfr[j] = *reinterpret_cast<const bf16x8*>(&Bs[cur][boff[j]]);
    #pragma unroll
    for (int i = 0; i < 4; ++i)
      #pragma unroll
      for (int j = 0; j < 4; ++j)
        acc[i][j] = __builtin_amdgcn_mfma_f32_16x16x32_bf16(af[i], bfr[j], acc[i][j], 0, 0, 0);
    cur = (cur == 2) ? 0 : cur + 1;
    nxt2 = (nxt2 == 2) ? 0 : nxt2 + 1;
  }

  // epilogue: C/D layout col=lane&15, row=quad*4+reg (m89-verified)
  #pragma unroll
  for (int i = 0; i < 4; ++i) {
    #pragma unroll
    for (int j = 0; j < 4; ++j) {
      const int row0 = bm * 128 + wm + i * 16 + lq * 4;
      const int col  = bn * 128 + wn + j * 16 + lr;
      #pragma unroll
      for (int r = 0; r < 4; ++r) {
        float v = acc[i][j][r] * alpha;
        if (BIAS_MODE == 1) v += bias[col];
        if (BIAS_MODE == 2) v += bias[row0 + r];
        storeC(C, (long)(row0 + r) * N + col, v);
      }
    }
  }
}

// =====================================================================
// Row softmax, exact reference ordering; bf16 Sc in, bf16 P out.
//   v = s[j]; if (mask[b,j]==0) v=-1e10; if (j>i) v += -1e10; softmax.
// =====================================================================
__global__ __launch_bounds__(256) void softmax_causal(
    const ushort_t* __restrict__ Sc, ushort_t* __restrict__ P,
    const int* __restrict__ mask, int S)
{
  const int i = blockIdx.x, b = blockIdx.y;
  const ushort_t* row = Sc + ((long)b * S + i) * S;
  ushort_t* prow = P + ((long)b * S + i) * S;
  const int* mrow = mask + (long)b * S;
  const int tid = threadIdx.x;
  const int lane = tid & 63, wave = tid >> 6;
  const int j0 = tid * 8;
  __shared__ float red[4];

  bf16x8 sv = *reinterpret_cast<const bf16x8*>(row + j0);
  const int4* mp = reinterpret_cast<const int4*>(mrow + j0);
  int4 m0 = mp[0], m1 = mp[1];
  int mk[8] = {m0.x, m0.y, m0.z, m0.w, m1.x, m1.y, m1.z, m1.w};

  float vals[8];
  float mymax = -3.4e38f;
  #pragma unroll
  for (int u = 0; u < 8; ++u) {
    const int j = j0 + u;
    float v = (float)sv[u];
    if (mk[u] == 0) v = -1e10f;
    if (j > i) v += -1e10f;
    vals[u] = v;
    mymax = fmaxf(mymax, v);
  }
  #pragma unroll
  for (int off = 32; off; off >>= 1)
    mymax = fmaxf(mymax, __shfl_xor(mymax, off));
  if (lane == 0) red[wave] = mymax;
  __syncthreads();
  const float m = fmaxf(fmaxf(red[0], red[1]), fmaxf(red[2], red[3]));
  __syncthreads();

  float sum = 0.f;
  #pragma unroll
  for (int u = 0; u < 8; ++u) {
    const float e = __expf(vals[u] - m);
    vals[u] = e;
    sum += e;
  }
  #pragma unroll
  for (int off = 32; off; off >>= 1)
    sum += __shfl_xor(sum, off);
  if (lane == 0) red[wave] = sum;
  __syncthreads();
  const float tot = red[0] + red[1] + red[2] + red[3];
  const float inv = 1.0f / tot;

  bf16x8 pv;
  #pragma unroll
  for (int u = 0; u < 8; ++u) pv[u] = (__bf16)(vals[u] * inv);
  *reinterpret_cast<bf16x8*>(prow + j0) = pv;
}

extern "C" void kernel_launch(void* const* d_in, const int* in_sizes, int n_in,
                              void* d_out, int out_size, void* d_ws, size_t ws_size,
                              hipStream_t stream)
{
  const int B = 4, S = 2048, D = 1024;
  const float* Q  = (const float*)d_in[0];
  const float* K  = (const float*)d_in[1];
  const float* V  = (const float*)d_in[2];
  const int*   am = (const int*)d_in[3];
  const float* Wq = (const float*)d_in[4];
  const float* bq = (const float*)d_in[5];
  const float* Wk = (const float*)d_in[6];
  const float* bk = (const float*)d_in[7];
  const float* Wv = (const float*)d_in[8];
  const float* bv = (const float*)d_in[9];
  float* out = (float*)d_out;

  const long MS = (long)B * S;       // 8192
  const long NQ = MS * D;            // 16 MB bf16
  const long NW = (long)D * D;       // 2 MB bf16

  // ws layout (102 MB + j0); aliases ordering-safe on the sequential stream:
  //  Sc(bf16,32MB) = Qb..Kb  (dead after projections)
  //  P (bf16,32MB) = qb..kb  (dead after scores GEMM)
  ushort_t* qb = (ushort_t*)d_ws;
  ushort_t* kb = qb + NQ;
  ushort_t* vT = kb + NQ;
  ushort_t* Qb = vT + NQ;
  ushort_t* Wqb = Qb + 3 * NQ;
  int* j0 = (int*)(Wqb + 3 * NW);
  ushort_t* Sc = Qb;                 // alias
  ushort_t* P  = qb;                 // alias

  dim3 blk(256);

  // converts (j0 scan folded into the first)
  cvt3<<<dim3((int)(NQ / 2048), 3), blk, 0, stream>>>(Q, K, V, Qb, NQ, am, j0, S, B);
  cvt3<<<dim3((int)(NW / 2048), 3), blk, 0, stream>>>(Wq, Wk, Wv, Wqb, NW,
                                                      nullptr, nullptr, S, B);

  // projections: z=0 -> q = Q·Wq^T+bq ; z=1 -> k = K·Wk^T+bk
  gemm_nt_bf16<ushort_t, 1, false><<<dim3(64, 8, 2), blk, 0, stream>>>(
      Qb, Wqb, bq, bk, qb, nullptr, (int)MS, D, D, 1.0f, NQ, NW, NQ);
  // vT[b,e,s] = sum_d Wv[e,d]*V[b,s,d] + bv[e]
  gemm_nt_bf16<ushort_t, 2, false><<<dim3(8, 16, 4), blk, 0, stream>>>(
      Wqb + 2 * NW, Qb + 2 * NQ, bv, nullptr, vT, nullptr,
      D, S, D, 1.0f, 0L, (long)S * D, (long)D * S);

  // Sc_b = q_b·k_b^T / sqrt(D), bf16 out, mask-safe causal tile skip
  gemm_nt_bf16<ushort_t, 0, true><<<dim3(16, 16, 4), blk, 0, stream>>>(
      qb, kb, nullptr, nullptr, Sc, j0, S, S, D, 0.03125f,
      (long)S * D, (long)S * D, (long)S * S);
  // softmax (mask + causal, reference ordering)
  softmax_causal<<<dim3(S, B), blk, 0, stream>>>(Sc, P, am, S);
  // O_b = P_b · vT_b^T
  gemm_nt_bf16<float, 0, false><<<dim3(16, 8, 4), blk, 0, stream>>>(
      P, vT, nullptr, nullptr, out, nullptr, S, D, S, 1.0f,
      (long)S * S, (long)D * S, (long)S * D);
}